// Round 6
// baseline (416.041 us; speedup 1.0000x reference)
//
#include <hip/hip_runtime.h>
#include <hip/hip_bf16.h>

// Problem constants (from reference)
constexpr int N  = 50000;   // nodes
constexpr int E  = 800000;  // edges
constexpr int D0 = 64;      // IN_DIM
constexpr int D1 = 128;     // HID_DIM

__device__ __forceinline__ void f4acc(float4& a, const float4 v) {
    a.x += v.x; a.y += v.y; a.z += v.z; a.w += v.w;
}

// ---------------------------------------------------------------------------
// CSR build step 1: count in-degree (int atomics, cheap)
// ---------------------------------------------------------------------------
__global__ void k_count(const int* __restrict__ dst, int* __restrict__ cnt) {
    int e = blockIdx.x * blockDim.x + threadIdx.x;
    if (e >= E) return;
    atomicAdd(&cnt[dst[e]], 1);
}

// ---------------------------------------------------------------------------
// CSR build step 2: exclusive scan of cnt[N] -> row_ptr[N+1], cursor[N].
// Single block, 1024 threads, chunked + Hillis-Steele on partial sums.
// cnt may alias cursor (each thread reads its chunk before any writes).
// ---------------------------------------------------------------------------
__global__ __launch_bounds__(1024)
void k_scan(const int* __restrict__ cnt, int* __restrict__ row_ptr,
            int* __restrict__ cursor) {
    constexpr int CH = (N + 1023) / 1024;  // 49
    __shared__ int ssum[1024];
    const int t = threadIdx.x;
    const int base = t * CH;

    int vals[CH];
    int local = 0;
    #pragma unroll
    for (int i = 0; i < CH; ++i) {
        int idx = base + i;
        int v = (idx < N) ? cnt[idx] : 0;
        vals[i] = v;
        local += v;
    }
    ssum[t] = local;
    __syncthreads();

    for (int off = 1; off < 1024; off <<= 1) {
        int v   = ssum[t];
        int add = (t >= off) ? ssum[t - off] : 0;
        __syncthreads();
        ssum[t] = v + add;
        __syncthreads();
    }

    int prefix = (t > 0) ? ssum[t - 1] : 0;  // exclusive prefix of this chunk
    #pragma unroll
    for (int i = 0; i < CH; ++i) {
        int idx = base + i;
        if (idx < N) { row_ptr[idx] = prefix; cursor[idx] = prefix; }
        prefix += vals[i];
    }
    if (t == 1023) row_ptr[N] = prefix;  // == E
}

// ---------------------------------------------------------------------------
// CSR build step 3: fill neighbor (source) lists sorted by dst
// ---------------------------------------------------------------------------
__global__ void k_fill(const int* __restrict__ src, const int* __restrict__ dst,
                       int* __restrict__ cursor, int* __restrict__ csr_src) {
    int e = blockIdx.x * blockDim.x + threadIdx.x;
    if (e >= E) return;
    int pos = atomicAdd(&cursor[dst[e]], 1);
    csr_src[pos] = src[e];
}

// ---------------------------------------------------------------------------
// Gather + mean: mean[n,:] = (1/max(deg,1)) * sum_{s in nbr(n)} xin[s,:]
// No LDS, __launch_bounds__(256,8) -> target 32 waves/CU.
// Sub-wave groups of GRPSZ = DIN/4 lanes, float4 per lane (one full row per
// group-load). 8 neighbor rows batched into 8 named registers before
// accumulation -> 8 loads in flight per group.
// ---------------------------------------------------------------------------
template<int DIN>
__global__ __launch_bounds__(256, 8)
void k_gather(const float* __restrict__ xin,
              const int* __restrict__ row_ptr,
              const int* __restrict__ csr_src,
              float* __restrict__ mean) {
    constexpr int GRPSZ = DIN / 4;      // 16 (DIN=64) or 32 (DIN=128)
    constexpr int GPB   = 256 / GRPSZ;  // groups per block: 16 or 8
    const int tid      = threadIdx.x;
    const int sub      = tid & (GRPSZ - 1);
    const int gloc     = tid / GRPSZ;
    const int lane     = tid & 63;
    const int lanebase = (lane / GRPSZ) * GRPSZ;  // first lane of group in wave
    const int g0   = blockIdx.x * GPB + gloc;
    const int gstr = gridDim.x * GPB;

    for (int n = g0; n < N; n += gstr) {
        const int start = row_ptr[n];
        const int end   = row_ptr[n + 1];

        float4 a0 = make_float4(0.f, 0.f, 0.f, 0.f);
        float4 a1 = a0, a2 = a0, a3 = a0;

        for (int b = start; b < end; b += GRPSZ) {
            int nb = (b + sub < end) ? csr_src[b + sub] : 0;
            const int cnt = min(GRPSZ, end - b);
            int j = 0;
            for (; j + 8 <= cnt; j += 8) {
                int s0 = __shfl(nb, lanebase + j + 0);
                int s1 = __shfl(nb, lanebase + j + 1);
                int s2 = __shfl(nb, lanebase + j + 2);
                int s3 = __shfl(nb, lanebase + j + 3);
                int s4 = __shfl(nb, lanebase + j + 4);
                int s5 = __shfl(nb, lanebase + j + 5);
                int s6 = __shfl(nb, lanebase + j + 6);
                int s7 = __shfl(nb, lanebase + j + 7);
                float4 v0 = *(const float4*)&xin[(size_t)s0 * DIN + sub * 4];
                float4 v1 = *(const float4*)&xin[(size_t)s1 * DIN + sub * 4];
                float4 v2 = *(const float4*)&xin[(size_t)s2 * DIN + sub * 4];
                float4 v3 = *(const float4*)&xin[(size_t)s3 * DIN + sub * 4];
                float4 v4 = *(const float4*)&xin[(size_t)s4 * DIN + sub * 4];
                float4 v5 = *(const float4*)&xin[(size_t)s5 * DIN + sub * 4];
                float4 v6 = *(const float4*)&xin[(size_t)s6 * DIN + sub * 4];
                float4 v7 = *(const float4*)&xin[(size_t)s7 * DIN + sub * 4];
                f4acc(a0, v0); f4acc(a1, v1); f4acc(a2, v2); f4acc(a3, v3);
                f4acc(a0, v4); f4acc(a1, v5); f4acc(a2, v6); f4acc(a3, v7);
            }
            for (; j < cnt; ++j) {
                int s = __shfl(nb, lanebase + j);
                float4 v = *(const float4*)&xin[(size_t)s * DIN + sub * 4];
                f4acc(a0, v);
            }
        }

        const float invd = 1.0f / fmaxf((float)(end - start), 1.0f);
        float4 r;
        r.x = (a0.x + a1.x + a2.x + a3.x) * invd;
        r.y = (a0.y + a1.y + a2.y + a3.y) * invd;
        r.z = (a0.z + a1.z + a2.z + a3.z) * invd;
        r.w = (a0.w + a1.w + a2.w + a3.w) * invd;
        *(float4*)&mean[(size_t)n * DIN + sub * 4] = r;
    }
}

// ---------------------------------------------------------------------------
// Dense: out[n,o] = relu?( mean[n,:] @ Wl[o,:] + xin[n,:] @ Wr[o,:] + b[o] )
// Register-tiled: 32 nodes x 128 outputs per block, 256 threads.
// Activations staged in LDS (float4); LDS reads are wave-broadcast
// (conflict-free). Weights float4 from L1/L2 (hot, tiny).
// ---------------------------------------------------------------------------
template<int DIN, bool RELU>
__global__ __launch_bounds__(256)
void k_dense(const float* __restrict__ mean,
             const float* __restrict__ xin,
             const float* __restrict__ Wl,
             const float* __restrict__ Wr,
             const float* __restrict__ bias,
             float* __restrict__ out,
             int n_nodes) {
    constexpr int DOUT = 128;
    constexpr int NT   = 32;     // nodes per block
    __shared__ float sm[NT][DIN];
    __shared__ float sx[NT][DIN];

    const int tid    = threadIdx.x;
    const int n_base = blockIdx.x * NT;

    // Stage activations: NT*DIN floats each, float4 granularity.
    constexpr int VECS = NT * DIN / 4;   // 512 or 1024
    for (int v = tid; v < VECS; v += 256) {
        int idx = v * 4;
        int r = idx / DIN;
        int c = idx - r * DIN;
        int n = n_base + r;
        float4 a, b;
        if (n < n_nodes) {
            a = *(const float4*)&mean[(size_t)n * DIN + c];
            b = *(const float4*)&xin[(size_t)n * DIN + c];
        } else {
            a = make_float4(0.f, 0.f, 0.f, 0.f);
            b = a;
        }
        *(float4*)&sm[r][c] = a;
        *(float4*)&sx[r][c] = b;
    }
    __syncthreads();

    const int o  = tid & (DOUT - 1);   // output feature
    const int nh = tid >> 7;           // node parity (0/1)

    float acc[NT / 2];
    #pragma unroll
    for (int j = 0; j < NT / 2; ++j) acc[j] = 0.0f;

    const float* wlrow = Wl + (size_t)o * DIN;
    const float* wrrow = Wr + (size_t)o * DIN;

    #pragma unroll 2
    for (int k0 = 0; k0 < DIN; k0 += 4) {
        float4 wl = *(const float4*)&wlrow[k0];
        float4 wr = *(const float4*)&wrrow[k0];
        #pragma unroll
        for (int j = 0; j < NT / 2; ++j) {
            int r = j * 2 + nh;
            float4 m  = *(const float4*)&sm[r][k0];
            float4 xv = *(const float4*)&sx[r][k0];
            acc[j] += m.x * wl.x + m.y * wl.y + m.z * wl.z + m.w * wl.w
                    + xv.x * wr.x + xv.y * wr.y + xv.z * wr.z + xv.w * wr.w;
        }
    }

    const float bv = bias[o];
    #pragma unroll
    for (int j = 0; j < NT / 2; ++j) {
        int r = j * 2 + nh;
        int n = n_base + r;
        if (n < n_nodes) {
            float v = acc[j] + bv;
            if constexpr (RELU) v = fmaxf(v, 0.0f);
            out[(size_t)n * DOUT + o] = v;
        }
    }
}

// ---------------------------------------------------------------------------
extern "C" void kernel_launch(void* const* d_in, const int* in_sizes, int n_in,
                              void* d_out, int out_size, void* d_ws, size_t ws_size,
                              hipStream_t stream) {
    const float* x   = (const float*)d_in[0];
    const int*   ei  = (const int*)d_in[1];   // [2, E] int32
    const float* W1l = (const float*)d_in[2];
    const float* W1r = (const float*)d_in[3];
    const float* b1  = (const float*)d_in[4];
    const float* W2l = (const float*)d_in[5];
    const float* W2r = (const float*)d_in[6];
    const float* b2  = (const float*)d_in[7];
    float*       out = (float*)d_out;

    const int* src = ei;       // edge_index[0]
    const int* dst = ei + E;   // edge_index[1]

    // Workspace layout (~55 MB):
    //   row_ptr int[N+1]
    //   cursor  int[N]      (also the count buffer)
    //   csr_src int[E]
    //   h       float[N*D1]
    //   mean    float[N*D1] (layer 1 uses first N*D0)
    int*   row_ptr = (int*)d_ws;
    int*   cursor  = row_ptr + (N + 1);
    int*   csr_src = cursor + N;
    float* h       = (float*)(csr_src + E);
    float* mean    = h + (size_t)N * D1;

    constexpr int NT = 32;
    const int nblk = (N + NT - 1) / NT;  // 1563

    // ---- CSR build (shared by both layers) ----
    hipMemsetAsync(cursor, 0, (size_t)N * sizeof(int), stream);
    k_count<<<(E + 255) / 256, 256, 0, stream>>>(dst, cursor);
    k_scan<<<1, 1024, 0, stream>>>(cursor, row_ptr, cursor);
    k_fill<<<(E + 255) / 256, 256, 0, stream>>>(src, dst, cursor, csr_src);

    // ---- Layer 1: x -> h (ReLU) ----
    k_gather<D0><<<2048, 256, 0, stream>>>(x, row_ptr, csr_src, mean);
    k_dense<D0, /*RELU=*/true>
        <<<nblk, 256, 0, stream>>>(mean, x, W1l, W1r, b1, h, N);

    // ---- Layer 2: h -> out ----
    k_gather<D1><<<2048, 256, 0, stream>>>(h, row_ptr, csr_src, mean);
    k_dense<D1, /*RELU=*/false>
        <<<nblk, 256, 0, stream>>>(mean, h, W2l, W2r, b2, out, N);
}

// Round 7
// 344.157 us; speedup vs baseline: 1.2089x; 1.2089x over previous
//
#include <hip/hip_runtime.h>
#include <hip/hip_bf16.h>

// Problem constants (from reference)
constexpr int N  = 50000;   // nodes
constexpr int E  = 800000;  // edges
constexpr int D0 = 64;      // IN_DIM
constexpr int D1 = 128;     // HID_DIM

typedef __attribute__((ext_vector_type(8))) short short8;   // 8 bf16 = 4 VGPR
typedef __attribute__((ext_vector_type(4))) float f32x4;

__device__ __forceinline__ void f4acc(float4& a, const float4 v) {
    a.x += v.x; a.y += v.y; a.z += v.z; a.w += v.w;
}

// ---------------------------------------------------------------------------
// CSR build step 1: count in-degree (int atomics, cheap)
// ---------------------------------------------------------------------------
__global__ void k_count(const int* __restrict__ dst, int* __restrict__ cnt) {
    int e = blockIdx.x * blockDim.x + threadIdx.x;
    if (e >= E) return;
    atomicAdd(&cnt[dst[e]], 1);
}

// ---------------------------------------------------------------------------
// CSR build step 2: exclusive scan of cnt[N] -> row_ptr[N+1], cursor[N].
// ---------------------------------------------------------------------------
__global__ __launch_bounds__(1024)
void k_scan(const int* __restrict__ cnt, int* __restrict__ row_ptr,
            int* __restrict__ cursor) {
    constexpr int CH = (N + 1023) / 1024;  // 49
    __shared__ int ssum[1024];
    const int t = threadIdx.x;
    const int base = t * CH;

    int vals[CH];
    int local = 0;
    #pragma unroll
    for (int i = 0; i < CH; ++i) {
        int idx = base + i;
        int v = (idx < N) ? cnt[idx] : 0;
        vals[i] = v;
        local += v;
    }
    ssum[t] = local;
    __syncthreads();

    for (int off = 1; off < 1024; off <<= 1) {
        int v   = ssum[t];
        int add = (t >= off) ? ssum[t - off] : 0;
        __syncthreads();
        ssum[t] = v + add;
        __syncthreads();
    }

    int prefix = (t > 0) ? ssum[t - 1] : 0;
    #pragma unroll
    for (int i = 0; i < CH; ++i) {
        int idx = base + i;
        if (idx < N) { row_ptr[idx] = prefix; cursor[idx] = prefix; }
        prefix += vals[i];
    }
    if (t == 1023) row_ptr[N] = prefix;  // == E
}

// ---------------------------------------------------------------------------
// CSR build step 3: fill neighbor (source) lists sorted by dst
// ---------------------------------------------------------------------------
__global__ void k_fill(const int* __restrict__ src, const int* __restrict__ dst,
                       int* __restrict__ cursor, int* __restrict__ csr_src) {
    int e = blockIdx.x * blockDim.x + threadIdx.x;
    if (e >= E) return;
    int pos = atomicAdd(&cursor[dst[e]], 1);
    csr_src[pos] = src[e];
}

// ---------------------------------------------------------------------------
// Weight prep: pack [Wl | Wr] rows into bf16 Wcat for both layers.
//   W1cat[o][k] k<64 -> W1l[o][k], else W1r[o][k-64]   (128 x 128)
//   W2cat[o][k] k<128-> W2l[o][k], else W2r[o][k-128]  (128 x 256)
// ---------------------------------------------------------------------------
__global__ void k_wprep(const float* __restrict__ W1l, const float* __restrict__ W1r,
                        const float* __restrict__ W2l, const float* __restrict__ W2r,
                        unsigned short* __restrict__ W1cat,
                        unsigned short* __restrict__ W2cat) {
    int i = blockIdx.x * blockDim.x + threadIdx.x;  // 0 .. 128*256
    if (i < 128 * 128) {
        int o = i >> 7, k = i & 127;
        float v = (k < 64) ? W1l[o * 64 + k] : W1r[o * 64 + (k - 64)];
        __hip_bfloat16 hb = __float2bfloat16(v);
        W1cat[i] = *reinterpret_cast<unsigned short*>(&hb);
    }
    if (i < 128 * 256) {
        int o = i >> 8, k = i & 255;
        float v = (k < 128) ? W2l[o * 128 + k] : W2r[o * 128 + (k - 128)];
        __hip_bfloat16 hb = __float2bfloat16(v);
        W2cat[i] = *reinterpret_cast<unsigned short*>(&hb);
    }
}

// ---------------------------------------------------------------------------
// Gather + mean: mean[n,:] = (1/max(deg,1)) * sum_{s in nbr(n)} xin[s,:]
// No LDS, __launch_bounds__(256,8). Sub-wave groups of DIN/4 lanes, float4
// per lane; 8 neighbor rows batched into named registers per iteration.
// ---------------------------------------------------------------------------
template<int DIN>
__global__ __launch_bounds__(256, 8)
void k_gather(const float* __restrict__ xin,
              const int* __restrict__ row_ptr,
              const int* __restrict__ csr_src,
              float* __restrict__ mean) {
    constexpr int GRPSZ = DIN / 4;      // 16 or 32
    constexpr int GPB   = 256 / GRPSZ;  // 16 or 8
    const int tid      = threadIdx.x;
    const int sub      = tid & (GRPSZ - 1);
    const int gloc     = tid / GRPSZ;
    const int lane     = tid & 63;
    const int lanebase = (lane / GRPSZ) * GRPSZ;
    const int g0   = blockIdx.x * GPB + gloc;
    const int gstr = gridDim.x * GPB;

    for (int n = g0; n < N; n += gstr) {
        const int start = row_ptr[n];
        const int end   = row_ptr[n + 1];

        float4 a0 = make_float4(0.f, 0.f, 0.f, 0.f);
        float4 a1 = a0, a2 = a0, a3 = a0;

        for (int b = start; b < end; b += GRPSZ) {
            int nb = (b + sub < end) ? csr_src[b + sub] : 0;
            const int cnt = min(GRPSZ, end - b);
            int j = 0;
            for (; j + 8 <= cnt; j += 8) {
                int s0 = __shfl(nb, lanebase + j + 0);
                int s1 = __shfl(nb, lanebase + j + 1);
                int s2 = __shfl(nb, lanebase + j + 2);
                int s3 = __shfl(nb, lanebase + j + 3);
                int s4 = __shfl(nb, lanebase + j + 4);
                int s5 = __shfl(nb, lanebase + j + 5);
                int s6 = __shfl(nb, lanebase + j + 6);
                int s7 = __shfl(nb, lanebase + j + 7);
                float4 v0 = *(const float4*)&xin[(size_t)s0 * DIN + sub * 4];
                float4 v1 = *(const float4*)&xin[(size_t)s1 * DIN + sub * 4];
                float4 v2 = *(const float4*)&xin[(size_t)s2 * DIN + sub * 4];
                float4 v3 = *(const float4*)&xin[(size_t)s3 * DIN + sub * 4];
                float4 v4 = *(const float4*)&xin[(size_t)s4 * DIN + sub * 4];
                float4 v5 = *(const float4*)&xin[(size_t)s5 * DIN + sub * 4];
                float4 v6 = *(const float4*)&xin[(size_t)s6 * DIN + sub * 4];
                float4 v7 = *(const float4*)&xin[(size_t)s7 * DIN + sub * 4];
                f4acc(a0, v0); f4acc(a1, v1); f4acc(a2, v2); f4acc(a3, v3);
                f4acc(a0, v4); f4acc(a1, v5); f4acc(a2, v6); f4acc(a3, v7);
            }
            for (; j < cnt; ++j) {
                int s = __shfl(nb, lanebase + j);
                float4 v = *(const float4*)&xin[(size_t)s * DIN + sub * 4];
                f4acc(a0, v);
            }
        }

        const float invd = 1.0f / fmaxf((float)(end - start), 1.0f);
        float4 r;
        r.x = (a0.x + a1.x + a2.x + a3.x) * invd;
        r.y = (a0.y + a1.y + a2.y + a3.y) * invd;
        r.z = (a0.z + a1.z + a2.z + a3.z) * invd;
        r.w = (a0.w + a1.w + a2.w + a3.w) * invd;
        *(float4*)&mean[(size_t)n * DIN + sub * 4] = r;
    }
}

// ---------------------------------------------------------------------------
// MFMA dense: out[n,:] = relu?( [mean[n]|xin[n]] @ Wcat^T + bias )
// K = 2*DIN (128 or 256). 64 nodes/block, 4 waves; each wave computes
// 16 nodes x 128 outs via 8 accumulator fragments of mfma_f32_16x16x32_bf16.
// A staged once in LDS as bf16, row padded +8 bf16 (row stride 528B for
// K=256 -> rows on distinct banks, worst 2-way = free). B fragments read
// from global Wcat (8KB working set per kk -> L1-hot).
// Fragment layouts (m89/m91-verified): A/B lane l -> (row=l&15,
// k=(l>>4)*8+j); C/D lane l -> (col=l&15, row=(l>>4)*4+i).
// ---------------------------------------------------------------------------
template<int DIN, bool RELU>
__global__ __launch_bounds__(256)
void k_mdense(const float* __restrict__ mean,
              const float* __restrict__ xin,
              const unsigned short* __restrict__ Wcat,  // [128][K] bf16
              const float* __restrict__ bias,
              float* __restrict__ out,
              int n_nodes) {
    constexpr int K  = 2 * DIN;       // 128 or 256
    constexpr int KP = K + 8;         // padded row length (bf16 units)
    __shared__ unsigned short A[64 * KP];

    const int tid   = threadIdx.x;
    const int nbase = blockIdx.x * 64;

    // ---- Stage A = [mean | xin] as bf16 into LDS ----
    constexpr int CPR   = K / 8;        // 8-elem chunks per row
    constexpr int TOTAL = 64 * CPR;     // 1024 or 2048
    for (int c = tid; c < TOTAL; c += 256) {
        int row  = c / CPR;
        int col8 = (c - row * CPR) * 8;
        int n    = nbase + row;
        float4 v0 = make_float4(0.f, 0.f, 0.f, 0.f), v1 = v0;
        if (n < n_nodes) {
            const float* srcp = (col8 < DIN)
                ? &mean[(size_t)n * DIN + col8]
                : &xin[(size_t)n * DIN + (col8 - DIN)];
            v0 = *(const float4*)srcp;
            v1 = *(const float4*)(srcp + 4);
        }
        unsigned short u[8];
        float f[8] = {v0.x, v0.y, v0.z, v0.w, v1.x, v1.y, v1.z, v1.w};
        #pragma unroll
        for (int j = 0; j < 8; ++j) {
            __hip_bfloat16 hb = __float2bfloat16(f[j]);
            u[j] = *reinterpret_cast<unsigned short*>(&hb);
        }
        *(short8*)&A[row * KP + col8] = *(short8*)u;
    }
    __syncthreads();

    // ---- MFMA: wave wv owns nodes [wv*16, wv*16+16) x all 128 outs ----
    const int lane = tid & 63;
    const int wv   = tid >> 6;
    const int l15  = lane & 15;   // A-row / B-row / C-col selector
    const int kseg = lane >> 4;   // k-segment / C-row-group selector

    f32x4 acc[8];
    #pragma unroll
    for (int ot = 0; ot < 8; ++ot) acc[ot] = (f32x4){0.f, 0.f, 0.f, 0.f};

    #pragma unroll
    for (int kk = 0; kk < K / 32; ++kk) {
        short8 a = *(const short8*)&A[(wv * 16 + l15) * KP + kk * 32 + kseg * 8];
        #pragma unroll
        for (int ot = 0; ot < 8; ++ot) {
            short8 b = *(const short8*)&Wcat[(size_t)(ot * 16 + l15) * K + kk * 32 + kseg * 8];
            acc[ot] = __builtin_amdgcn_mfma_f32_16x16x32_bf16(a, b, acc[ot], 0, 0, 0);
        }
    }

    // ---- Epilogue: bias (+ReLU), write f32 ----
    #pragma unroll
    for (int ot = 0; ot < 8; ++ot) {
        const int o  = ot * 16 + l15;
        const float bv = bias[o];
        #pragma unroll
        for (int i = 0; i < 4; ++i) {
            int n = nbase + wv * 16 + kseg * 4 + i;
            if (n < n_nodes) {
                float v = acc[ot][i] + bv;
                if constexpr (RELU) v = fmaxf(v, 0.0f);
                out[(size_t)n * 128 + o] = v;
            }
        }
    }
}

// ---------------------------------------------------------------------------
extern "C" void kernel_launch(void* const* d_in, const int* in_sizes, int n_in,
                              void* d_out, int out_size, void* d_ws, size_t ws_size,
                              hipStream_t stream) {
    const float* x   = (const float*)d_in[0];
    const int*   ei  = (const int*)d_in[1];   // [2, E] int32
    const float* W1l = (const float*)d_in[2];
    const float* W1r = (const float*)d_in[3];
    const float* b1  = (const float*)d_in[4];
    const float* W2l = (const float*)d_in[5];
    const float* W2r = (const float*)d_in[6];
    const float* b2  = (const float*)d_in[7];
    float*       out = (float*)d_out;

    const int* src = ei;       // edge_index[0]
    const int* dst = ei + E;   // edge_index[1]

    // Workspace layout (~55.2 MB):
    //   row_ptr int[N+1]; cursor int[N]; csr_src int[E];
    //   h float[N*D1]; mean float[N*D1];
    //   W1cat bf16[128*128]; W2cat bf16[128*256]
    int*            row_ptr = (int*)d_ws;
    int*            cursor  = row_ptr + (N + 1);
    int*            csr_src = cursor + N;
    float*          h       = (float*)(csr_src + E);
    float*          mean    = h + (size_t)N * D1;
    unsigned short* W1cat   = (unsigned short*)(mean + (size_t)N * D1);
    unsigned short* W2cat   = W1cat + 128 * 128;

    const int nblk_d = (N + 63) / 64;  // 782

    // ---- CSR build + weight prep ----
    hipMemsetAsync(cursor, 0, (size_t)N * sizeof(int), stream);
    k_count<<<(E + 255) / 256, 256, 0, stream>>>(dst, cursor);
    k_scan<<<1, 1024, 0, stream>>>(cursor, row_ptr, cursor);
    k_fill<<<(E + 255) / 256, 256, 0, stream>>>(src, dst, cursor, csr_src);
    k_wprep<<<(128 * 256 + 255) / 256, 256, 0, stream>>>(W1l, W1r, W2l, W2r, W1cat, W2cat);

    // ---- Layer 1: x -> h (ReLU) ----
    k_gather<D0><<<2048, 256, 0, stream>>>(x, row_ptr, csr_src, mean);
    k_mdense<D0, /*RELU=*/true>
        <<<nblk_d, 256, 0, stream>>>(mean, x, W1cat, b1, h, N);

    // ---- Layer 2: h -> out ----
    k_gather<D1><<<2048, 256, 0, stream>>>(h, row_ptr, csr_src, mean);
    k_mdense<D1, /*RELU=*/false>
        <<<nblk_d, 256, 0, stream>>>(mean, h, W2cat, b2, out, N);
}

// Round 8
// 230.185 us; speedup vs baseline: 1.8074x; 1.4951x over previous
//
#include <hip/hip_runtime.h>
#include <hip/hip_bf16.h>

// Problem constants (from reference)
constexpr int N  = 50000;   // nodes
constexpr int E  = 800000;  // edges
constexpr int D0 = 64;      // IN_DIM
constexpr int D1 = 128;     // HID_DIM

typedef __attribute__((ext_vector_type(8))) short short8;   // 8 bf16 = 4 VGPR
typedef __attribute__((ext_vector_type(4))) float f32x4;

__device__ __forceinline__ unsigned short bf16bits(float f) {
    __hip_bfloat16 hb = __float2bfloat16(f);
    return *reinterpret_cast<unsigned short*>(&hb);
}

// accumulate 8 bf16 (packed in uint4) into 8 f32 accumulators
__device__ __forceinline__ void acc8(float* a, const uint4 r) {
    union { unsigned u; float f; } c;
    c.u = r.x << 16;         a[0] += c.f;
    c.u = r.x & 0xffff0000u; a[1] += c.f;
    c.u = r.y << 16;         a[2] += c.f;
    c.u = r.y & 0xffff0000u; a[3] += c.f;
    c.u = r.z << 16;         a[4] += c.f;
    c.u = r.z & 0xffff0000u; a[5] += c.f;
    c.u = r.w << 16;         a[6] += c.f;
    c.u = r.w & 0xffff0000u; a[7] += c.f;
}

// ---------------------------------------------------------------------------
// CSR build step 1: count in-degree (int atomics, cheap)
// ---------------------------------------------------------------------------
__global__ void k_count(const int* __restrict__ dst, int* __restrict__ cnt) {
    int e = blockIdx.x * blockDim.x + threadIdx.x;
    if (e >= E) return;
    atomicAdd(&cnt[dst[e]], 1);
}

// ---------------------------------------------------------------------------
// CSR build step 2: multi-block exclusive scan (3 phases, each ~2-4 us;
// replaces the 84 us single-block scan seen in round 7's profile).
// ---------------------------------------------------------------------------
constexpr int SCAN_BLK = 1024;
constexpr int NSB = (N + SCAN_BLK - 1) / SCAN_BLK;  // 49 (<= 64)

// phase a: block-local exclusive scan of cnt -> row_ptr; block totals -> bsum
__global__ __launch_bounds__(1024)
void k_scan_a(const int* __restrict__ cnt, int* __restrict__ lscan,
              int* __restrict__ bsum) {
    __shared__ int s[1024];
    const int t   = threadIdx.x;
    const int gid = blockIdx.x * 1024 + t;
    int v = (gid < N) ? cnt[gid] : 0;
    s[t] = v;
    __syncthreads();
    for (int off = 1; off < 1024; off <<= 1) {
        int a = s[t];
        int b = (t >= off) ? s[t - off] : 0;
        __syncthreads();
        s[t] = a + b;
        __syncthreads();
    }
    if (gid < N) lscan[gid] = s[t] - v;   // exclusive
    if (t == 1023) bsum[blockIdx.x] = s[1023];
}

// phase b: single-wave scan of the NSB block sums -> exclusive offsets
__global__ void k_scan_b(const int* __restrict__ bsum, int* __restrict__ boff,
                         int* __restrict__ row_ptr) {
    const int t = threadIdx.x;  // 64 threads
    int orig = (t < NSB) ? bsum[t] : 0;
    int v = orig;
    #pragma unroll
    for (int off = 1; off < 64; off <<= 1) {
        int u = __shfl_up(v, off);
        if (t >= off) v += u;
    }
    if (t < NSB) boff[t] = v - orig;      // exclusive
    if (t == 63) row_ptr[N] = v;          // total == E
}

// phase c: add block offsets in place; also init cursor
__global__ __launch_bounds__(1024)
void k_scan_c(int* __restrict__ row_ptr, int* __restrict__ cursor,
              const int* __restrict__ boff) {
    const int gid = blockIdx.x * 1024 + threadIdx.x;
    if (gid < N) {
        int v = row_ptr[gid] + boff[blockIdx.x];
        row_ptr[gid] = v;
        cursor[gid]  = v;
    }
}

// ---------------------------------------------------------------------------
// CSR build step 3: fill neighbor (source) lists sorted by dst
// ---------------------------------------------------------------------------
__global__ void k_fill(const int* __restrict__ src, const int* __restrict__ dst,
                       int* __restrict__ cursor, int* __restrict__ csr_src) {
    int e = blockIdx.x * blockDim.x + threadIdx.x;
    if (e >= E) return;
    int pos = atomicAdd(&cursor[dst[e]], 1);
    csr_src[pos] = src[e];
}

// ---------------------------------------------------------------------------
// Convert x (f32) -> bf16 once; both gather-1 and dense-1 read the bf16 copy.
// ---------------------------------------------------------------------------
__global__ void k_cvtx(const float* __restrict__ x, unsigned short* __restrict__ xb) {
    int i = blockIdx.x * blockDim.x + threadIdx.x;  // one per 8 elements
    if (i >= N * D0 / 8) return;
    const float4 v0 = *(const float4*)&x[(size_t)i * 8];
    const float4 v1 = *(const float4*)&x[(size_t)i * 8 + 4];
    float f[8] = {v0.x, v0.y, v0.z, v0.w, v1.x, v1.y, v1.z, v1.w};
    unsigned short u[8];
    #pragma unroll
    for (int j = 0; j < 8; ++j) u[j] = bf16bits(f[j]);
    *(short8*)&xb[(size_t)i * 8] = *(short8*)u;
}

// ---------------------------------------------------------------------------
// Weight prep: pack [Wl | Wr] rows into bf16 Wcat for both layers.
// ---------------------------------------------------------------------------
__global__ void k_wprep(const float* __restrict__ W1l, const float* __restrict__ W1r,
                        const float* __restrict__ W2l, const float* __restrict__ W2r,
                        unsigned short* __restrict__ W1cat,
                        unsigned short* __restrict__ W2cat) {
    int i = blockIdx.x * blockDim.x + threadIdx.x;  // 0 .. 128*256
    if (i < 128 * 128) {
        int o = i >> 7, k = i & 127;
        float v = (k < 64) ? W1l[o * 64 + k] : W1r[o * 64 + (k - 64)];
        W1cat[i] = bf16bits(v);
    }
    if (i < 128 * 256) {
        int o = i >> 8, k = i & 255;
        float v = (k < 128) ? W2l[o * 128 + k] : W2r[o * 128 + (k - 128)];
        W2cat[i] = bf16bits(v);
    }
}

// ---------------------------------------------------------------------------
// Gather + mean over bf16 features: mean[n,:] = sum_nbr(xin) / max(deg,1)
// Sub-wave groups of DIN/8 lanes, 16B (short8) per lane -> one full row per
// group-load. 4 neighbor rows batched in flight; f32 accumulation
// (bf16->f32 decode is 2 bit-ops per pair). Output mean as bf16.
// ---------------------------------------------------------------------------
template<int DIN>
__global__ __launch_bounds__(256, 8)
void k_gather(const unsigned short* __restrict__ xin,  // bf16 [N][DIN]
              const int* __restrict__ row_ptr,
              const int* __restrict__ csr_src,
              unsigned short* __restrict__ mean) {     // bf16 [N][DIN]
    constexpr int GRPSZ = DIN / 8;      // 8 (D0) or 16 (D1)
    constexpr int GPB   = 256 / GRPSZ;  // 32 or 16
    const int tid      = threadIdx.x;
    const int sub      = tid & (GRPSZ - 1);
    const int gloc     = tid / GRPSZ;
    const int lane     = tid & 63;
    const int lanebase = (lane / GRPSZ) * GRPSZ;
    const int g0   = blockIdx.x * GPB + gloc;
    const int gstr = gridDim.x * GPB;

    for (int n = g0; n < N; n += gstr) {
        const int start = row_ptr[n];
        const int end   = row_ptr[n + 1];

        float a[8] = {0.f, 0.f, 0.f, 0.f, 0.f, 0.f, 0.f, 0.f};

        for (int b = start; b < end; b += GRPSZ) {
            int nb = (b + sub < end) ? csr_src[b + sub] : 0;
            const int cnt = min(GRPSZ, end - b);
            int j = 0;
            for (; j + 4 <= cnt; j += 4) {
                int s0 = __shfl(nb, lanebase + j + 0);
                int s1 = __shfl(nb, lanebase + j + 1);
                int s2 = __shfl(nb, lanebase + j + 2);
                int s3 = __shfl(nb, lanebase + j + 3);
                uint4 r0 = *(const uint4*)&xin[(size_t)s0 * DIN + sub * 8];
                uint4 r1 = *(const uint4*)&xin[(size_t)s1 * DIN + sub * 8];
                uint4 r2 = *(const uint4*)&xin[(size_t)s2 * DIN + sub * 8];
                uint4 r3 = *(const uint4*)&xin[(size_t)s3 * DIN + sub * 8];
                acc8(a, r0); acc8(a, r1); acc8(a, r2); acc8(a, r3);
            }
            for (; j < cnt; ++j) {
                int s = __shfl(nb, lanebase + j);
                uint4 r = *(const uint4*)&xin[(size_t)s * DIN + sub * 8];
                acc8(a, r);
            }
        }

        const float invd = 1.0f / fmaxf((float)(end - start), 1.0f);
        unsigned short u[8];
        #pragma unroll
        for (int q = 0; q < 8; ++q) u[q] = bf16bits(a[q] * invd);
        *(short8*)&mean[(size_t)n * DIN + sub * 8] = *(short8*)u;
    }
}

// ---------------------------------------------------------------------------
// MFMA dense: out[n,:] = relu?( [mean[n]|xin[n]] @ Wcat^T + bias )
// K = 2*DIN. 64 nodes/block, 4 waves; each wave: 16 nodes x 128 outs via 8
// accumulator fragments of mfma_f32_16x16x32_bf16. A staged in LDS (bf16,
// straight short8 copy since inputs are already bf16), row padded +8.
// B fragments from global Wcat (L1-hot). Fragment layouts per m89/m91.
// ---------------------------------------------------------------------------
template<int DIN, bool RELU, bool OUT_BF16>
__global__ __launch_bounds__(256)
void k_mdense(const unsigned short* __restrict__ mean,
              const unsigned short* __restrict__ xin,
              const unsigned short* __restrict__ Wcat,  // [128][K] bf16
              const float* __restrict__ bias,
              void* __restrict__ out,
              int n_nodes) {
    constexpr int K  = 2 * DIN;       // 128 or 256
    constexpr int KP = K + 8;         // padded row (bf16 units)
    __shared__ unsigned short A[64 * KP];

    const int tid   = threadIdx.x;
    const int nbase = blockIdx.x * 64;

    // ---- Stage A = [mean | xin] (bf16 copy) ----
    constexpr int CPR   = K / 8;
    constexpr int TOTAL = 64 * CPR;
    for (int c = tid; c < TOTAL; c += 256) {
        int row  = c / CPR;
        int col8 = (c - row * CPR) * 8;
        int n    = nbase + row;
        short8 v = (short8)0;
        if (n < n_nodes) {
            const unsigned short* srcp = (col8 < DIN)
                ? &mean[(size_t)n * DIN + col8]
                : &xin[(size_t)n * DIN + (col8 - DIN)];
            v = *(const short8*)srcp;
        }
        *(short8*)&A[row * KP + col8] = v;
    }
    __syncthreads();

    // ---- MFMA ----
    const int lane = tid & 63;
    const int wv   = tid >> 6;
    const int l15  = lane & 15;
    const int kseg = lane >> 4;

    f32x4 acc[8];
    #pragma unroll
    for (int ot = 0; ot < 8; ++ot) acc[ot] = (f32x4){0.f, 0.f, 0.f, 0.f};

    #pragma unroll
    for (int kk = 0; kk < K / 32; ++kk) {
        short8 a = *(const short8*)&A[(wv * 16 + l15) * KP + kk * 32 + kseg * 8];
        #pragma unroll
        for (int ot = 0; ot < 8; ++ot) {
            short8 b = *(const short8*)&Wcat[(size_t)(ot * 16 + l15) * K + kk * 32 + kseg * 8];
            acc[ot] = __builtin_amdgcn_mfma_f32_16x16x32_bf16(a, b, acc[ot], 0, 0, 0);
        }
    }

    // ---- Epilogue ----
    #pragma unroll
    for (int ot = 0; ot < 8; ++ot) {
        const int o  = ot * 16 + l15;
        const float bv = bias[o];
        #pragma unroll
        for (int i = 0; i < 4; ++i) {
            int n = nbase + wv * 16 + kseg * 4 + i;
            if (n < n_nodes) {
                float v = acc[ot][i] + bv;
                if constexpr (RELU) v = fmaxf(v, 0.0f);
                if constexpr (OUT_BF16) {
                    ((unsigned short*)out)[(size_t)n * 128 + o] = bf16bits(v);
                } else {
                    ((float*)out)[(size_t)n * 128 + o] = v;
                }
            }
        }
    }
}

// ---------------------------------------------------------------------------
extern "C" void kernel_launch(void* const* d_in, const int* in_sizes, int n_in,
                              void* d_out, int out_size, void* d_ws, size_t ws_size,
                              hipStream_t stream) {
    const float* x   = (const float*)d_in[0];
    const int*   ei  = (const int*)d_in[1];   // [2, E] int32
    const float* W1l = (const float*)d_in[2];
    const float* W1r = (const float*)d_in[3];
    const float* b1  = (const float*)d_in[4];
    const float* W2l = (const float*)d_in[5];
    const float* W2r = (const float*)d_in[6];
    const float* b2  = (const float*)d_in[7];
    float*       out = (float*)d_out;

    const int* src = ei;       // edge_index[0]
    const int* dst = ei + E;   // edge_index[1]

    // Workspace (16B-aligned bump allocator), ~36 MB total
    char* p = (char*)d_ws;
    auto alloc = [&](size_t bytes) -> char* {
        char* r = p; p += (bytes + 15) & ~(size_t)15; return r;
    };
    int*            row_ptr = (int*)alloc((N + 1) * sizeof(int));
    int*            cursor  = (int*)alloc(N * sizeof(int));
    int*            csr_src = (int*)alloc((size_t)E * sizeof(int));
    int*            bsum    = (int*)alloc(64 * sizeof(int));
    int*            boff    = (int*)alloc(64 * sizeof(int));
    unsigned short* xb      = (unsigned short*)alloc((size_t)N * D0 * 2);
    unsigned short* h       = (unsigned short*)alloc((size_t)N * D1 * 2);
    unsigned short* mean    = (unsigned short*)alloc((size_t)N * D1 * 2);
    unsigned short* W1cat   = (unsigned short*)alloc(128 * 128 * 2);
    unsigned short* W2cat   = (unsigned short*)alloc(128 * 256 * 2);

    const int nblk_d = (N + 63) / 64;  // 782

    // ---- prep (independent of CSR) ----
    k_cvtx<<<(N * D0 / 8 + 255) / 256, 256, 0, stream>>>(x, xb);
    k_wprep<<<(128 * 256 + 255) / 256, 256, 0, stream>>>(W1l, W1r, W2l, W2r, W1cat, W2cat);

    // ---- CSR build ----
    hipMemsetAsync(cursor, 0, (size_t)N * sizeof(int), stream);
    k_count<<<(E + 255) / 256, 256, 0, stream>>>(dst, cursor);
    k_scan_a<<<NSB, 1024, 0, stream>>>(cursor, row_ptr, bsum);
    k_scan_b<<<1, 64, 0, stream>>>(bsum, boff, row_ptr);
    k_scan_c<<<NSB, 1024, 0, stream>>>(row_ptr, cursor, boff);
    k_fill<<<(E + 255) / 256, 256, 0, stream>>>(src, dst, cursor, csr_src);

    // ---- Layer 1: xb -> h (ReLU, bf16) ----
    k_gather<D0><<<2048, 256, 0, stream>>>(xb, row_ptr, csr_src, mean);
    k_mdense<D0, /*RELU=*/true, /*OUT_BF16=*/true>
        <<<nblk_d, 256, 0, stream>>>(mean, xb, W1cat, b1, h, N);

    // ---- Layer 2: h -> out (f32) ----
    k_gather<D1><<<2048, 256, 0, stream>>>(h, row_ptr, csr_src, mean);
    k_mdense<D1, /*RELU=*/false, /*OUT_BF16=*/false>
        <<<nblk_d, 256, 0, stream>>>(mean, h, W2cat, b2, out, N);
}

// Round 9
// 182.632 us; speedup vs baseline: 2.2780x; 1.2604x over previous
//
#include <hip/hip_runtime.h>
#include <hip/hip_bf16.h>

// Problem constants (from reference)
constexpr int N  = 50000;   // nodes
constexpr int E  = 800000;  // edges
constexpr int D0 = 64;      // IN_DIM
constexpr int D1 = 128;     // HID_DIM
constexpr int CAP = 64;     // per-node neighbor capacity (Poisson(16) tail:
                            // P(deg>=64) ~ 2e-18/node; guarded anyway)

typedef __attribute__((ext_vector_type(8))) short short8;   // 8 bf16 = 4 VGPR
typedef __attribute__((ext_vector_type(4))) float f32x4;

__device__ __forceinline__ unsigned short bf16bits(float f) {
    __hip_bfloat16 hb = __float2bfloat16(f);
    return *reinterpret_cast<unsigned short*>(&hb);
}

// accumulate 8 bf16 (packed in uint4) into 8 f32 accumulators
__device__ __forceinline__ void acc8(float* a, const uint4 r) {
    union { unsigned u; float f; } c;
    c.u = r.x << 16;         a[0] += c.f;
    c.u = r.x & 0xffff0000u; a[1] += c.f;
    c.u = r.y << 16;         a[2] += c.f;
    c.u = r.y & 0xffff0000u; a[3] += c.f;
    c.u = r.z << 16;         a[4] += c.f;
    c.u = r.z & 0xffff0000u; a[5] += c.f;
    c.u = r.w << 16;         a[6] += c.f;
    c.u = r.w & 0xffff0000u; a[7] += c.f;
}

// ---------------------------------------------------------------------------
// Direct binning: bin[dst][pos] = src, pos from one atomic pass.
// Replaces count+scan+fill (two atomic passes + 3 scan launches).
// 4 edges per thread, int4 loads, 4 independent atomic->write chains.
// ---------------------------------------------------------------------------
__global__ void k_bin(const int* __restrict__ src, const int* __restrict__ dst,
                      int* __restrict__ cnt, int* __restrict__ bin) {
    int i = blockIdx.x * blockDim.x + threadIdx.x;
    int e0 = i * 4;                      // E % 4 == 0, no tail
    if (e0 >= E) return;
    int4 d = *(const int4*)&dst[e0];
    int4 s = *(const int4*)&src[e0];
    int p0 = atomicAdd(&cnt[d.x], 1);
    int p1 = atomicAdd(&cnt[d.y], 1);
    int p2 = atomicAdd(&cnt[d.z], 1);
    int p3 = atomicAdd(&cnt[d.w], 1);
    if (p0 < CAP) bin[d.x * CAP + p0] = s.x;
    if (p1 < CAP) bin[d.y * CAP + p1] = s.y;
    if (p2 < CAP) bin[d.z * CAP + p2] = s.z;
    if (p3 < CAP) bin[d.w * CAP + p3] = s.w;
}

// ---------------------------------------------------------------------------
// Convert x (f32) -> bf16 once; both gather-1 and dense-1 read the bf16 copy.
// ---------------------------------------------------------------------------
__global__ void k_cvtx(const float* __restrict__ x, unsigned short* __restrict__ xb) {
    int i = blockIdx.x * blockDim.x + threadIdx.x;  // one per 8 elements
    if (i >= N * D0 / 8) return;
    const float4 v0 = *(const float4*)&x[(size_t)i * 8];
    const float4 v1 = *(const float4*)&x[(size_t)i * 8 + 4];
    float f[8] = {v0.x, v0.y, v0.z, v0.w, v1.x, v1.y, v1.z, v1.w};
    unsigned short u[8];
    #pragma unroll
    for (int j = 0; j < 8; ++j) u[j] = bf16bits(f[j]);
    *(short8*)&xb[(size_t)i * 8] = *(short8*)u;
}

// ---------------------------------------------------------------------------
// Weight prep: pack [Wl | Wr] rows into bf16 Wcat for both layers.
// ---------------------------------------------------------------------------
__global__ void k_wprep(const float* __restrict__ W1l, const float* __restrict__ W1r,
                        const float* __restrict__ W2l, const float* __restrict__ W2r,
                        unsigned short* __restrict__ W1cat,
                        unsigned short* __restrict__ W2cat) {
    int i = blockIdx.x * blockDim.x + threadIdx.x;  // 0 .. 128*256
    if (i < 128 * 128) {
        int o = i >> 7, k = i & 127;
        float v = (k < 64) ? W1l[o * 64 + k] : W1r[o * 64 + (k - 64)];
        W1cat[i] = bf16bits(v);
    }
    if (i < 128 * 256) {
        int o = i >> 8, k = i & 255;
        float v = (k < 128) ? W2l[o * 128 + k] : W2r[o * 128 + (k - 128)];
        W2cat[i] = bf16bits(v);
    }
}

// ---------------------------------------------------------------------------
// Gather + mean over bf16 features: mean[n,:] = sum_nbr(xin) / max(deg,1)
// Neighbor lists at fixed stride CAP. Sub-wave groups of DIN/8 lanes,
// 16B (short8) per lane; 4 neighbor rows in flight; f32 accumulation.
// ---------------------------------------------------------------------------
template<int DIN>
__global__ __launch_bounds__(256, 8)
void k_gather(const unsigned short* __restrict__ xin,  // bf16 [N][DIN]
              const int* __restrict__ cnt,
              const int* __restrict__ bin,             // [N][CAP]
              unsigned short* __restrict__ mean) {     // bf16 [N][DIN]
    constexpr int GRPSZ = DIN / 8;      // 8 (D0) or 16 (D1)
    constexpr int GPB   = 256 / GRPSZ;  // 32 or 16
    const int tid      = threadIdx.x;
    const int sub      = tid & (GRPSZ - 1);
    const int gloc     = tid / GRPSZ;
    const int lane     = tid & 63;
    const int lanebase = (lane / GRPSZ) * GRPSZ;
    const int g0   = blockIdx.x * GPB + gloc;
    const int gstr = gridDim.x * GPB;

    for (int n = g0; n < N; n += gstr) {
        const int deg  = cnt[n];
        const int degc = min(deg, CAP);
        const int base = n * CAP;

        float a[8] = {0.f, 0.f, 0.f, 0.f, 0.f, 0.f, 0.f, 0.f};

        for (int b = 0; b < degc; b += GRPSZ) {
            int nb = (b + sub < degc) ? bin[base + b + sub] : 0;
            const int c = min(GRPSZ, degc - b);
            int j = 0;
            for (; j + 4 <= c; j += 4) {
                int s0 = __shfl(nb, lanebase + j + 0);
                int s1 = __shfl(nb, lanebase + j + 1);
                int s2 = __shfl(nb, lanebase + j + 2);
                int s3 = __shfl(nb, lanebase + j + 3);
                uint4 r0 = *(const uint4*)&xin[(size_t)s0 * DIN + sub * 8];
                uint4 r1 = *(const uint4*)&xin[(size_t)s1 * DIN + sub * 8];
                uint4 r2 = *(const uint4*)&xin[(size_t)s2 * DIN + sub * 8];
                uint4 r3 = *(const uint4*)&xin[(size_t)s3 * DIN + sub * 8];
                acc8(a, r0); acc8(a, r1); acc8(a, r2); acc8(a, r3);
            }
            for (; j < c; ++j) {
                int s = __shfl(nb, lanebase + j);
                uint4 r = *(const uint4*)&xin[(size_t)s * DIN + sub * 8];
                acc8(a, r);
            }
        }

        const float invd = 1.0f / fmaxf((float)deg, 1.0f);
        unsigned short u[8];
        #pragma unroll
        for (int q = 0; q < 8; ++q) u[q] = bf16bits(a[q] * invd);
        *(short8*)&mean[(size_t)n * DIN + sub * 8] = *(short8*)u;
    }
}

// ---------------------------------------------------------------------------
// MFMA dense: out[n,:] = relu?( [mean[n]|xin[n]] @ Wcat^T + bias )
// K = 2*DIN. 64 nodes/block, 4 waves; each wave: 16 nodes x 128 outs via 8
// accumulator fragments of mfma_f32_16x16x32_bf16. A staged in LDS (bf16
// short8 copy), row padded +8. B from global Wcat (L1-hot).
// Fragment layouts per m89/m91.
// ---------------------------------------------------------------------------
template<int DIN, bool RELU, bool OUT_BF16>
__global__ __launch_bounds__(256)
void k_mdense(const unsigned short* __restrict__ mean,
              const unsigned short* __restrict__ xin,
              const unsigned short* __restrict__ Wcat,  // [128][K] bf16
              const float* __restrict__ bias,
              void* __restrict__ out,
              int n_nodes) {
    constexpr int K  = 2 * DIN;       // 128 or 256
    constexpr int KP = K + 8;         // padded row (bf16 units)
    __shared__ unsigned short A[64 * KP];

    const int tid   = threadIdx.x;
    const int nbase = blockIdx.x * 64;

    // ---- Stage A = [mean | xin] (bf16 copy) ----
    constexpr int CPR   = K / 8;
    constexpr int TOTAL = 64 * CPR;
    for (int c = tid; c < TOTAL; c += 256) {
        int row  = c / CPR;
        int col8 = (c - row * CPR) * 8;
        int n    = nbase + row;
        short8 v = (short8)0;
        if (n < n_nodes) {
            const unsigned short* srcp = (col8 < DIN)
                ? &mean[(size_t)n * DIN + col8]
                : &xin[(size_t)n * DIN + (col8 - DIN)];
            v = *(const short8*)srcp;
        }
        *(short8*)&A[row * KP + col8] = v;
    }
    __syncthreads();

    // ---- MFMA ----
    const int lane = tid & 63;
    const int wv   = tid >> 6;
    const int l15  = lane & 15;
    const int kseg = lane >> 4;

    f32x4 acc[8];
    #pragma unroll
    for (int ot = 0; ot < 8; ++ot) acc[ot] = (f32x4){0.f, 0.f, 0.f, 0.f};

    #pragma unroll
    for (int kk = 0; kk < K / 32; ++kk) {
        short8 a = *(const short8*)&A[(wv * 16 + l15) * KP + kk * 32 + kseg * 8];
        #pragma unroll
        for (int ot = 0; ot < 8; ++ot) {
            short8 b = *(const short8*)&Wcat[(size_t)(ot * 16 + l15) * K + kk * 32 + kseg * 8];
            acc[ot] = __builtin_amdgcn_mfma_f32_16x16x32_bf16(a, b, acc[ot], 0, 0, 0);
        }
    }

    // ---- Epilogue ----
    #pragma unroll
    for (int ot = 0; ot < 8; ++ot) {
        const int o  = ot * 16 + l15;
        const float bv = bias[o];
        #pragma unroll
        for (int i = 0; i < 4; ++i) {
            int n = nbase + wv * 16 + kseg * 4 + i;
            if (n < n_nodes) {
                float v = acc[ot][i] + bv;
                if constexpr (RELU) v = fmaxf(v, 0.0f);
                if constexpr (OUT_BF16) {
                    ((unsigned short*)out)[(size_t)n * 128 + o] = bf16bits(v);
                } else {
                    ((float*)out)[(size_t)n * 128 + o] = v;
                }
            }
        }
    }
}

// ---------------------------------------------------------------------------
extern "C" void kernel_launch(void* const* d_in, const int* in_sizes, int n_in,
                              void* d_out, int out_size, void* d_ws, size_t ws_size,
                              hipStream_t stream) {
    const float* x   = (const float*)d_in[0];
    const int*   ei  = (const int*)d_in[1];   // [2, E] int32
    const float* W1l = (const float*)d_in[2];
    const float* W1r = (const float*)d_in[3];
    const float* b1  = (const float*)d_in[4];
    const float* W2l = (const float*)d_in[5];
    const float* W2r = (const float*)d_in[6];
    const float* b2  = (const float*)d_in[7];
    float*       out = (float*)d_out;

    const int* src = ei;       // edge_index[0]
    const int* dst = ei + E;   // edge_index[1]

    // Workspace (16B-aligned bump allocator), ~33 MB total
    char* p = (char*)d_ws;
    auto alloc = [&](size_t bytes) -> char* {
        char* r = p; p += (bytes + 15) & ~(size_t)15; return r;
    };
    int*            cnt   = (int*)alloc(N * sizeof(int));
    int*            bin   = (int*)alloc((size_t)N * CAP * sizeof(int));  // 12.8 MB
    unsigned short* xb    = (unsigned short*)alloc((size_t)N * D0 * 2);
    unsigned short* h     = (unsigned short*)alloc((size_t)N * D1 * 2);
    unsigned short* mean  = (unsigned short*)alloc((size_t)N * D1 * 2);
    unsigned short* W1cat = (unsigned short*)alloc(128 * 128 * 2);
    unsigned short* W2cat = (unsigned short*)alloc(128 * 256 * 2);

    const int nblk_d = (N + 63) / 64;  // 782

    // ---- prep (independent of binning) ----
    k_cvtx<<<(N * D0 / 8 + 255) / 256, 256, 0, stream>>>(x, xb);
    k_wprep<<<(128 * 256 + 255) / 256, 256, 0, stream>>>(W1l, W1r, W2l, W2r, W1cat, W2cat);

    // ---- adjacency build: one atomic pass ----
    hipMemsetAsync(cnt, 0, (size_t)N * sizeof(int), stream);
    k_bin<<<(E / 4 + 255) / 256, 256, 0, stream>>>(src, dst, cnt, bin);

    // ---- Layer 1: xb -> h (ReLU, bf16) ----
    k_gather<D0><<<2048, 256, 0, stream>>>(xb, cnt, bin, mean);
    k_mdense<D0, /*RELU=*/true, /*OUT_BF16=*/true>
        <<<nblk_d, 256, 0, stream>>>(mean, xb, W1cat, b1, h, N);

    // ---- Layer 2: h -> out (f32) ----
    k_gather<D1><<<2048, 256, 0, stream>>>(h, cnt, bin, mean);
    k_mdense<D1, /*RELU=*/false, /*OUT_BF16=*/false>
        <<<nblk_d, 256, 0, stream>>>(mean, h, W2cat, b2, out, N);
}

// Round 10
// 173.055 us; speedup vs baseline: 2.4041x; 1.0553x over previous
//
#include <hip/hip_runtime.h>
#include <hip/hip_bf16.h>

// Problem constants (from reference)
constexpr int N  = 50000;   // nodes
constexpr int E  = 800000;  // edges
constexpr int D0 = 64;      // IN_DIM
constexpr int D1 = 128;     // HID_DIM
constexpr int CAP = 64;     // per-node neighbor capacity (Poisson(16) tail:
                            // P(deg>=64) ~ 2e-18/node; guarded anyway)

constexpr int NPART = 8;                       // XCD count
constexpr int PSZ   = (N + NPART - 1) / NPART; // 6250 nodes per partition
constexpr int BPP   = 128;                     // blocks per partition

typedef __attribute__((ext_vector_type(8))) short short8;   // 8 bf16 = 4 VGPR
typedef __attribute__((ext_vector_type(4))) float f32x4;

__device__ __forceinline__ unsigned short bf16bits(float f) {
    __hip_bfloat16 hb = __float2bfloat16(f);
    return *reinterpret_cast<unsigned short*>(&hb);
}

// accumulate 8 bf16 (packed in uint4) into 8 f32 accumulators
__device__ __forceinline__ void acc8(float* a, const uint4 r) {
    union { unsigned u; float f; } c;
    c.u = r.x << 16;         a[0] += c.f;
    c.u = r.x & 0xffff0000u; a[1] += c.f;
    c.u = r.y << 16;         a[2] += c.f;
    c.u = r.y & 0xffff0000u; a[3] += c.f;
    c.u = r.z << 16;         a[4] += c.f;
    c.u = r.z & 0xffff0000u; a[5] += c.f;
    c.u = r.w << 16;         a[6] += c.f;
    c.u = r.w & 0xffff0000u; a[7] += c.f;
}

// ---------------------------------------------------------------------------
// XCD-partitioned binning: blocks with blockIdx%8==p handle dst range
// [p*PSZ, (p+1)*PSZ). All writes/atomics to a node's bin line then come from
// ONE XCD -> line accumulates ~deg entries in that XCD's L2, written back
// once (vs round 9: 47 MB write traffic for a 3.2 MB payload because all 8
// XCDs touched every line). Edge list re-read 8x but L3-resident.
// Partition choice is a locality heuristic only -- correctness does not
// depend on the workgroup->XCD mapping (G16).
// ---------------------------------------------------------------------------
__global__ __launch_bounds__(256)
void k_bin(const int* __restrict__ src, const int* __restrict__ dst,
           int* __restrict__ cnt, int* __restrict__ bin) {
    const int p     = blockIdx.x & (NPART - 1);   // partition = XCD guess
    const int local = blockIdx.x >> 3;            // 0..BPP-1
    const int lo = p * PSZ;
    const int hi = min(N, lo + PSZ);

    for (int i = local * 256 + threadIdx.x; i < E / 4; i += BPP * 256) {
        const int e0 = i * 4;
        int4 d = *(const int4*)&dst[e0];
        int4 s = *(const int4*)&src[e0];
        if (d.x >= lo && d.x < hi) {
            int pos = atomicAdd(&cnt[d.x], 1);
            if (pos < CAP) bin[d.x * CAP + pos] = s.x;
        }
        if (d.y >= lo && d.y < hi) {
            int pos = atomicAdd(&cnt[d.y], 1);
            if (pos < CAP) bin[d.y * CAP + pos] = s.y;
        }
        if (d.z >= lo && d.z < hi) {
            int pos = atomicAdd(&cnt[d.z], 1);
            if (pos < CAP) bin[d.z * CAP + pos] = s.z;
        }
        if (d.w >= lo && d.w < hi) {
            int pos = atomicAdd(&cnt[d.w], 1);
            if (pos < CAP) bin[d.w * CAP + pos] = s.w;
        }
    }
}

// ---------------------------------------------------------------------------
// Convert x (f32) -> bf16 once; both gather-1 and dense-1 read the bf16 copy.
// ---------------------------------------------------------------------------
__global__ void k_cvtx(const float* __restrict__ x, unsigned short* __restrict__ xb) {
    int i = blockIdx.x * blockDim.x + threadIdx.x;  // one per 8 elements
    if (i >= N * D0 / 8) return;
    const float4 v0 = *(const float4*)&x[(size_t)i * 8];
    const float4 v1 = *(const float4*)&x[(size_t)i * 8 + 4];
    float f[8] = {v0.x, v0.y, v0.z, v0.w, v1.x, v1.y, v1.z, v1.w};
    unsigned short u[8];
    #pragma unroll
    for (int j = 0; j < 8; ++j) u[j] = bf16bits(f[j]);
    *(short8*)&xb[(size_t)i * 8] = *(short8*)u;
}

// ---------------------------------------------------------------------------
// Weight prep: pack [Wl | Wr] rows into bf16 Wcat for both layers.
// ---------------------------------------------------------------------------
__global__ void k_wprep(const float* __restrict__ W1l, const float* __restrict__ W1r,
                        const float* __restrict__ W2l, const float* __restrict__ W2r,
                        unsigned short* __restrict__ W1cat,
                        unsigned short* __restrict__ W2cat) {
    int i = blockIdx.x * blockDim.x + threadIdx.x;  // 0 .. 128*256
    if (i < 128 * 128) {
        int o = i >> 7, k = i & 127;
        float v = (k < 64) ? W1l[o * 64 + k] : W1r[o * 64 + (k - 64)];
        W1cat[i] = bf16bits(v);
    }
    if (i < 128 * 256) {
        int o = i >> 8, k = i & 255;
        float v = (k < 128) ? W2l[o * 128 + k] : W2r[o * 128 + (k - 128)];
        W2cat[i] = bf16bits(v);
    }
}

// ---------------------------------------------------------------------------
// Gather + mean over bf16 features: mean[n,:] = sum_nbr(xin) / max(deg,1)
// Neighbor lists at fixed stride CAP. Sub-wave groups of DIN/8 lanes,
// 16B (short8) per lane; 4 neighbor rows in flight; f32 accumulation.
// ---------------------------------------------------------------------------
template<int DIN>
__global__ __launch_bounds__(256, 8)
void k_gather(const unsigned short* __restrict__ xin,  // bf16 [N][DIN]
              const int* __restrict__ cnt,
              const int* __restrict__ bin,             // [N][CAP]
              unsigned short* __restrict__ mean) {     // bf16 [N][DIN]
    constexpr int GRPSZ = DIN / 8;      // 8 (D0) or 16 (D1)
    constexpr int GPB   = 256 / GRPSZ;  // 32 or 16
    const int tid      = threadIdx.x;
    const int sub      = tid & (GRPSZ - 1);
    const int gloc     = tid / GRPSZ;
    const int lane     = tid & 63;
    const int lanebase = (lane / GRPSZ) * GRPSZ;
    const int g0   = blockIdx.x * GPB + gloc;
    const int gstr = gridDim.x * GPB;

    for (int n = g0; n < N; n += gstr) {
        const int deg  = cnt[n];
        const int degc = min(deg, CAP);
        const int base = n * CAP;

        float a[8] = {0.f, 0.f, 0.f, 0.f, 0.f, 0.f, 0.f, 0.f};

        for (int b = 0; b < degc; b += GRPSZ) {
            int nb = (b + sub < degc) ? bin[base + b + sub] : 0;
            const int c = min(GRPSZ, degc - b);
            int j = 0;
            for (; j + 4 <= c; j += 4) {
                int s0 = __shfl(nb, lanebase + j + 0);
                int s1 = __shfl(nb, lanebase + j + 1);
                int s2 = __shfl(nb, lanebase + j + 2);
                int s3 = __shfl(nb, lanebase + j + 3);
                uint4 r0 = *(const uint4*)&xin[(size_t)s0 * DIN + sub * 8];
                uint4 r1 = *(const uint4*)&xin[(size_t)s1 * DIN + sub * 8];
                uint4 r2 = *(const uint4*)&xin[(size_t)s2 * DIN + sub * 8];
                uint4 r3 = *(const uint4*)&xin[(size_t)s3 * DIN + sub * 8];
                acc8(a, r0); acc8(a, r1); acc8(a, r2); acc8(a, r3);
            }
            for (; j < c; ++j) {
                int s = __shfl(nb, lanebase + j);
                uint4 r = *(const uint4*)&xin[(size_t)s * DIN + sub * 8];
                acc8(a, r);
            }
        }

        const float invd = 1.0f / fmaxf((float)deg, 1.0f);
        unsigned short u[8];
        #pragma unroll
        for (int q = 0; q < 8; ++q) u[q] = bf16bits(a[q] * invd);
        *(short8*)&mean[(size_t)n * DIN + sub * 8] = *(short8*)u;
    }
}

// ---------------------------------------------------------------------------
// MFMA dense: out[n,:] = relu?( [mean[n]|xin[n]] @ Wcat^T + bias )
// K = 2*DIN. 64 nodes/block, 4 waves; each wave: 16 nodes x 128 outs via 8
// accumulator fragments of mfma_f32_16x16x32_bf16. A staged in LDS (bf16
// short8 copy), row padded +8. B from global Wcat (L1-hot).
// Fragment layouts per m89/m91.
// ---------------------------------------------------------------------------
template<int DIN, bool RELU, bool OUT_BF16>
__global__ __launch_bounds__(256)
void k_mdense(const unsigned short* __restrict__ mean,
              const unsigned short* __restrict__ xin,
              const unsigned short* __restrict__ Wcat,  // [128][K] bf16
              const float* __restrict__ bias,
              void* __restrict__ out,
              int n_nodes) {
    constexpr int K  = 2 * DIN;       // 128 or 256
    constexpr int KP = K + 8;         // padded row (bf16 units)
    __shared__ unsigned short A[64 * KP];

    const int tid   = threadIdx.x;
    const int nbase = blockIdx.x * 64;

    // ---- Stage A = [mean | xin] (bf16 copy) ----
    constexpr int CPR   = K / 8;
    constexpr int TOTAL = 64 * CPR;
    for (int c = tid; c < TOTAL; c += 256) {
        int row  = c / CPR;
        int col8 = (c - row * CPR) * 8;
        int n    = nbase + row;
        short8 v = (short8)0;
        if (n < n_nodes) {
            const unsigned short* srcp = (col8 < DIN)
                ? &mean[(size_t)n * DIN + col8]
                : &xin[(size_t)n * DIN + (col8 - DIN)];
            v = *(const short8*)srcp;
        }
        *(short8*)&A[row * KP + col8] = v;
    }
    __syncthreads();

    // ---- MFMA ----
    const int lane = tid & 63;
    const int wv   = tid >> 6;
    const int l15  = lane & 15;
    const int kseg = lane >> 4;

    f32x4 acc[8];
    #pragma unroll
    for (int ot = 0; ot < 8; ++ot) acc[ot] = (f32x4){0.f, 0.f, 0.f, 0.f};

    #pragma unroll
    for (int kk = 0; kk < K / 32; ++kk) {
        short8 a = *(const short8*)&A[(wv * 16 + l15) * KP + kk * 32 + kseg * 8];
        #pragma unroll
        for (int ot = 0; ot < 8; ++ot) {
            short8 b = *(const short8*)&Wcat[(size_t)(ot * 16 + l15) * K + kk * 32 + kseg * 8];
            acc[ot] = __builtin_amdgcn_mfma_f32_16x16x32_bf16(a, b, acc[ot], 0, 0, 0);
        }
    }

    // ---- Epilogue ----
    #pragma unroll
    for (int ot = 0; ot < 8; ++ot) {
        const int o  = ot * 16 + l15;
        const float bv = bias[o];
        #pragma unroll
        for (int i = 0; i < 4; ++i) {
            int n = nbase + wv * 16 + kseg * 4 + i;
            if (n < n_nodes) {
                float v = acc[ot][i] + bv;
                if constexpr (RELU) v = fmaxf(v, 0.0f);
                if constexpr (OUT_BF16) {
                    ((unsigned short*)out)[(size_t)n * 128 + o] = bf16bits(v);
                } else {
                    ((float*)out)[(size_t)n * 128 + o] = v;
                }
            }
        }
    }
}

// ---------------------------------------------------------------------------
extern "C" void kernel_launch(void* const* d_in, const int* in_sizes, int n_in,
                              void* d_out, int out_size, void* d_ws, size_t ws_size,
                              hipStream_t stream) {
    const float* x   = (const float*)d_in[0];
    const int*   ei  = (const int*)d_in[1];   // [2, E] int32
    const float* W1l = (const float*)d_in[2];
    const float* W1r = (const float*)d_in[3];
    const float* b1  = (const float*)d_in[4];
    const float* W2l = (const float*)d_in[5];
    const float* W2r = (const float*)d_in[6];
    const float* b2  = (const float*)d_in[7];
    float*       out = (float*)d_out;

    const int* src = ei;       // edge_index[0]
    const int* dst = ei + E;   // edge_index[1]

    // Workspace (16B-aligned bump allocator), ~33 MB total
    char* p = (char*)d_ws;
    auto alloc = [&](size_t bytes) -> char* {
        char* r = p; p += (bytes + 15) & ~(size_t)15; return r;
    };
    int*            cnt   = (int*)alloc(N * sizeof(int));
    int*            bin   = (int*)alloc((size_t)N * CAP * sizeof(int));  // 12.8 MB
    unsigned short* xb    = (unsigned short*)alloc((size_t)N * D0 * 2);
    unsigned short* h     = (unsigned short*)alloc((size_t)N * D1 * 2);
    unsigned short* mean  = (unsigned short*)alloc((size_t)N * D1 * 2);
    unsigned short* W1cat = (unsigned short*)alloc(128 * 128 * 2);
    unsigned short* W2cat = (unsigned short*)alloc(128 * 256 * 2);

    const int nblk_d = (N + 63) / 64;  // 782

    // ---- prep (independent of binning) ----
    k_cvtx<<<(N * D0 / 8 + 255) / 256, 256, 0, stream>>>(x, xb);
    k_wprep<<<(128 * 256 + 255) / 256, 256, 0, stream>>>(W1l, W1r, W2l, W2r, W1cat, W2cat);

    // ---- adjacency build: one XCD-partitioned atomic pass ----
    hipMemsetAsync(cnt, 0, (size_t)N * sizeof(int), stream);
    k_bin<<<NPART * BPP, 256, 0, stream>>>(src, dst, cnt, bin);

    // ---- Layer 1: xb -> h (ReLU, bf16) ----
    k_gather<D0><<<2048, 256, 0, stream>>>(xb, cnt, bin, mean);
    k_mdense<D0, /*RELU=*/true, /*OUT_BF16=*/true>
        <<<nblk_d, 256, 0, stream>>>(mean, xb, W1cat, b1, h, N);

    // ---- Layer 2: h -> out (f32) ----
    k_gather<D1><<<2048, 256, 0, stream>>>(h, cnt, bin, mean);
    k_mdense<D1, /*RELU=*/false, /*OUT_BF16=*/false>
        <<<nblk_d, 256, 0, stream>>>(mean, h, W2cat, b2, out, N);
}

// Round 11
// 172.453 us; speedup vs baseline: 2.4125x; 1.0035x over previous
//
#include <hip/hip_runtime.h>
#include <hip/hip_bf16.h>

// Problem constants (from reference)
constexpr int N  = 50000;   // nodes
constexpr int E  = 800000;  // edges
constexpr int D0 = 64;      // IN_DIM
constexpr int D1 = 128;     // HID_DIM
constexpr int CAP = 64;     // per-node neighbor capacity (Poisson(16) tail:
                            // P(deg>=64) ~ 2e-18/node; guarded anyway)

constexpr int NPART = 8;                       // XCD count
constexpr int PSZ   = (N + NPART - 1) / NPART; // 6250 nodes per partition
constexpr int BPP   = 128;                     // blocks per partition

typedef __attribute__((ext_vector_type(8))) short short8;   // 8 bf16 = 4 VGPR
typedef __attribute__((ext_vector_type(4))) float f32x4;

__device__ __forceinline__ unsigned short bf16bits(float f) {
    __hip_bfloat16 hb = __float2bfloat16(f);
    return *reinterpret_cast<unsigned short*>(&hb);
}

// accumulate 8 bf16 (packed in uint4) into 8 f32 accumulators
__device__ __forceinline__ void acc8(float* a, const uint4 r) {
    union { unsigned u; float f; } c;
    c.u = r.x << 16;         a[0] += c.f;
    c.u = r.x & 0xffff0000u; a[1] += c.f;
    c.u = r.y << 16;         a[2] += c.f;
    c.u = r.y & 0xffff0000u; a[3] += c.f;
    c.u = r.z << 16;         a[4] += c.f;
    c.u = r.z & 0xffff0000u; a[5] += c.f;
    c.u = r.w << 16;         a[6] += c.f;
    c.u = r.w & 0xffff0000u; a[7] += c.f;
}

// ---------------------------------------------------------------------------
// Zero the cnt buffer ourselves: the HIP runtime's fillBufferAligned kernel
// took 44 us per replay for 200 KB (tiny fixed grid, 4.7 GB/s). 12500 int4
// stores across 49 blocks do it at full width.
// ---------------------------------------------------------------------------
__global__ void k_zero(int4* __restrict__ p, int n4) {
    int i = blockIdx.x * blockDim.x + threadIdx.x;
    if (i < n4) p[i] = make_int4(0, 0, 0, 0);
}

// ---------------------------------------------------------------------------
// XCD-partitioned binning: blocks with blockIdx%8==p handle dst range
// [p*PSZ, (p+1)*PSZ). All writes/atomics to a node's bin line then come from
// ONE XCD -> line accumulates ~deg entries in that XCD's L2, written back
// once. Edge list re-read 8x but L3-resident. Partition choice is a
// locality heuristic only -- correctness does not depend on the
// workgroup->XCD mapping (G16).
// ---------------------------------------------------------------------------
__global__ __launch_bounds__(256)
void k_bin(const int* __restrict__ src, const int* __restrict__ dst,
           int* __restrict__ cnt, int* __restrict__ bin) {
    const int p     = blockIdx.x & (NPART - 1);   // partition = XCD guess
    const int local = blockIdx.x >> 3;            // 0..BPP-1
    const int lo = p * PSZ;
    const int hi = min(N, lo + PSZ);

    for (int i = local * 256 + threadIdx.x; i < E / 4; i += BPP * 256) {
        const int e0 = i * 4;
        int4 d = *(const int4*)&dst[e0];
        int4 s = *(const int4*)&src[e0];
        if (d.x >= lo && d.x < hi) {
            int pos = atomicAdd(&cnt[d.x], 1);
            if (pos < CAP) bin[d.x * CAP + pos] = s.x;
        }
        if (d.y >= lo && d.y < hi) {
            int pos = atomicAdd(&cnt[d.y], 1);
            if (pos < CAP) bin[d.y * CAP + pos] = s.y;
        }
        if (d.z >= lo && d.z < hi) {
            int pos = atomicAdd(&cnt[d.z], 1);
            if (pos < CAP) bin[d.z * CAP + pos] = s.z;
        }
        if (d.w >= lo && d.w < hi) {
            int pos = atomicAdd(&cnt[d.w], 1);
            if (pos < CAP) bin[d.w * CAP + pos] = s.w;
        }
    }
}

// ---------------------------------------------------------------------------
// Convert x (f32) -> bf16 once; both gather-1 and dense-1 read the bf16 copy.
// ---------------------------------------------------------------------------
__global__ void k_cvtx(const float* __restrict__ x, unsigned short* __restrict__ xb) {
    int i = blockIdx.x * blockDim.x + threadIdx.x;  // one per 8 elements
    if (i >= N * D0 / 8) return;
    const float4 v0 = *(const float4*)&x[(size_t)i * 8];
    const float4 v1 = *(const float4*)&x[(size_t)i * 8 + 4];
    float f[8] = {v0.x, v0.y, v0.z, v0.w, v1.x, v1.y, v1.z, v1.w};
    unsigned short u[8];
    #pragma unroll
    for (int j = 0; j < 8; ++j) u[j] = bf16bits(f[j]);
    *(short8*)&xb[(size_t)i * 8] = *(short8*)u;
}

// ---------------------------------------------------------------------------
// Weight prep: pack [Wl | Wr] rows into bf16 Wcat for both layers.
// ---------------------------------------------------------------------------
__global__ void k_wprep(const float* __restrict__ W1l, const float* __restrict__ W1r,
                        const float* __restrict__ W2l, const float* __restrict__ W2r,
                        unsigned short* __restrict__ W1cat,
                        unsigned short* __restrict__ W2cat) {
    int i = blockIdx.x * blockDim.x + threadIdx.x;  // 0 .. 128*256
    if (i < 128 * 128) {
        int o = i >> 7, k = i & 127;
        float v = (k < 64) ? W1l[o * 64 + k] : W1r[o * 64 + (k - 64)];
        W1cat[i] = bf16bits(v);
    }
    if (i < 128 * 256) {
        int o = i >> 8, k = i & 255;
        float v = (k < 128) ? W2l[o * 128 + k] : W2r[o * 128 + (k - 128)];
        W2cat[i] = bf16bits(v);
    }
}

// ---------------------------------------------------------------------------
// Gather + mean over bf16 features: mean[n,:] = sum_nbr(xin) / max(deg,1)
// Neighbor lists at fixed stride CAP. Sub-wave groups of DIN/8 lanes,
// 16B (short8) per lane; 4 neighbor rows in flight; f32 accumulation.
// ---------------------------------------------------------------------------
template<int DIN>
__global__ __launch_bounds__(256, 8)
void k_gather(const unsigned short* __restrict__ xin,  // bf16 [N][DIN]
              const int* __restrict__ cnt,
              const int* __restrict__ bin,             // [N][CAP]
              unsigned short* __restrict__ mean) {     // bf16 [N][DIN]
    constexpr int GRPSZ = DIN / 8;      // 8 (D0) or 16 (D1)
    constexpr int GPB   = 256 / GRPSZ;  // 32 or 16
    const int tid      = threadIdx.x;
    const int sub      = tid & (GRPSZ - 1);
    const int gloc     = tid / GRPSZ;
    const int lane     = tid & 63;
    const int lanebase = (lane / GRPSZ) * GRPSZ;
    const int g0   = blockIdx.x * GPB + gloc;
    const int gstr = gridDim.x * GPB;

    for (int n = g0; n < N; n += gstr) {
        const int deg  = cnt[n];
        const int degc = min(deg, CAP);
        const int base = n * CAP;

        float a[8] = {0.f, 0.f, 0.f, 0.f, 0.f, 0.f, 0.f, 0.f};

        for (int b = 0; b < degc; b += GRPSZ) {
            int nb = (b + sub < degc) ? bin[base + b + sub] : 0;
            const int c = min(GRPSZ, degc - b);
            int j = 0;
            for (; j + 4 <= c; j += 4) {
                int s0 = __shfl(nb, lanebase + j + 0);
                int s1 = __shfl(nb, lanebase + j + 1);
                int s2 = __shfl(nb, lanebase + j + 2);
                int s3 = __shfl(nb, lanebase + j + 3);
                uint4 r0 = *(const uint4*)&xin[(size_t)s0 * DIN + sub * 8];
                uint4 r1 = *(const uint4*)&xin[(size_t)s1 * DIN + sub * 8];
                uint4 r2 = *(const uint4*)&xin[(size_t)s2 * DIN + sub * 8];
                uint4 r3 = *(const uint4*)&xin[(size_t)s3 * DIN + sub * 8];
                acc8(a, r0); acc8(a, r1); acc8(a, r2); acc8(a, r3);
            }
            for (; j < c; ++j) {
                int s = __shfl(nb, lanebase + j);
                uint4 r = *(const uint4*)&xin[(size_t)s * DIN + sub * 8];
                acc8(a, r);
            }
        }

        const float invd = 1.0f / fmaxf((float)deg, 1.0f);
        unsigned short u[8];
        #pragma unroll
        for (int q = 0; q < 8; ++q) u[q] = bf16bits(a[q] * invd);
        *(short8*)&mean[(size_t)n * DIN + sub * 8] = *(short8*)u;
    }
}

// ---------------------------------------------------------------------------
// MFMA dense: out[n,:] = relu?( [mean[n]|xin[n]] @ Wcat^T + bias )
// K = 2*DIN. 64 nodes/block, 4 waves; each wave: 16 nodes x 128 outs via 8
// accumulator fragments of mfma_f32_16x16x32_bf16. A staged in LDS (bf16
// short8 copy), row padded +8. B from global Wcat (L1-hot).
// Fragment layouts per m89/m91.
// ---------------------------------------------------------------------------
template<int DIN, bool RELU, bool OUT_BF16>
__global__ __launch_bounds__(256)
void k_mdense(const unsigned short* __restrict__ mean,
              const unsigned short* __restrict__ xin,
              const unsigned short* __restrict__ Wcat,  // [128][K] bf16
              const float* __restrict__ bias,
              void* __restrict__ out,
              int n_nodes) {
    constexpr int K  = 2 * DIN;       // 128 or 256
    constexpr int KP = K + 8;         // padded row (bf16 units)
    __shared__ unsigned short A[64 * KP];

    const int tid   = threadIdx.x;
    const int nbase = blockIdx.x * 64;

    // ---- Stage A = [mean | xin] (bf16 copy) ----
    constexpr int CPR   = K / 8;
    constexpr int TOTAL = 64 * CPR;
    for (int c = tid; c < TOTAL; c += 256) {
        int row  = c / CPR;
        int col8 = (c - row * CPR) * 8;
        int n    = nbase + row;
        short8 v = (short8)0;
        if (n < n_nodes) {
            const unsigned short* srcp = (col8 < DIN)
                ? &mean[(size_t)n * DIN + col8]
                : &xin[(size_t)n * DIN + (col8 - DIN)];
            v = *(const short8*)srcp;
        }
        *(short8*)&A[row * KP + col8] = v;
    }
    __syncthreads();

    // ---- MFMA ----
    const int lane = tid & 63;
    const int wv   = tid >> 6;
    const int l15  = lane & 15;
    const int kseg = lane >> 4;

    f32x4 acc[8];
    #pragma unroll
    for (int ot = 0; ot < 8; ++ot) acc[ot] = (f32x4){0.f, 0.f, 0.f, 0.f};

    #pragma unroll
    for (int kk = 0; kk < K / 32; ++kk) {
        short8 a = *(const short8*)&A[(wv * 16 + l15) * KP + kk * 32 + kseg * 8];
        #pragma unroll
        for (int ot = 0; ot < 8; ++ot) {
            short8 b = *(const short8*)&Wcat[(size_t)(ot * 16 + l15) * K + kk * 32 + kseg * 8];
            acc[ot] = __builtin_amdgcn_mfma_f32_16x16x32_bf16(a, b, acc[ot], 0, 0, 0);
        }
    }

    // ---- Epilogue ----
    #pragma unroll
    for (int ot = 0; ot < 8; ++ot) {
        const int o  = ot * 16 + l15;
        const float bv = bias[o];
        #pragma unroll
        for (int i = 0; i < 4; ++i) {
            int n = nbase + wv * 16 + kseg * 4 + i;
            if (n < n_nodes) {
                float v = acc[ot][i] + bv;
                if constexpr (RELU) v = fmaxf(v, 0.0f);
                if constexpr (OUT_BF16) {
                    ((unsigned short*)out)[(size_t)n * 128 + o] = bf16bits(v);
                } else {
                    ((float*)out)[(size_t)n * 128 + o] = v;
                }
            }
        }
    }
}

// ---------------------------------------------------------------------------
extern "C" void kernel_launch(void* const* d_in, const int* in_sizes, int n_in,
                              void* d_out, int out_size, void* d_ws, size_t ws_size,
                              hipStream_t stream) {
    const float* x   = (const float*)d_in[0];
    const int*   ei  = (const int*)d_in[1];   // [2, E] int32
    const float* W1l = (const float*)d_in[2];
    const float* W1r = (const float*)d_in[3];
    const float* b1  = (const float*)d_in[4];
    const float* W2l = (const float*)d_in[5];
    const float* W2r = (const float*)d_in[6];
    const float* b2  = (const float*)d_in[7];
    float*       out = (float*)d_out;

    const int* src = ei;       // edge_index[0]
    const int* dst = ei + E;   // edge_index[1]

    // Workspace (16B-aligned bump allocator), ~33 MB total
    char* p = (char*)d_ws;
    auto alloc = [&](size_t bytes) -> char* {
        char* r = p; p += (bytes + 15) & ~(size_t)15; return r;
    };
    int*            cnt   = (int*)alloc(N * sizeof(int));
    int*            bin   = (int*)alloc((size_t)N * CAP * sizeof(int));  // 12.8 MB
    unsigned short* xb    = (unsigned short*)alloc((size_t)N * D0 * 2);
    unsigned short* h     = (unsigned short*)alloc((size_t)N * D1 * 2);
    unsigned short* mean  = (unsigned short*)alloc((size_t)N * D1 * 2);
    unsigned short* W1cat = (unsigned short*)alloc(128 * 128 * 2);
    unsigned short* W2cat = (unsigned short*)alloc(128 * 256 * 2);

    const int nblk_d = (N + 63) / 64;  // 782

    // ---- prep (independent of binning) ----
    k_cvtx<<<(N * D0 / 8 + 255) / 256, 256, 0, stream>>>(x, xb);
    k_wprep<<<(128 * 256 + 255) / 256, 256, 0, stream>>>(W1l, W1r, W2l, W2r, W1cat, W2cat);

    // ---- adjacency build: zero counts + one XCD-partitioned atomic pass ----
    {
        constexpr int N4 = N / 4;  // 12500 int4s (N % 4 == 0)
        k_zero<<<(N4 + 255) / 256, 256, 0, stream>>>((int4*)cnt, N4);
    }
    k_bin<<<NPART * BPP, 256, 0, stream>>>(src, dst, cnt, bin);

    // ---- Layer 1: xb -> h (ReLU, bf16) ----
    k_gather<D0><<<2048, 256, 0, stream>>>(xb, cnt, bin, mean);
    k_mdense<D0, /*RELU=*/true, /*OUT_BF16=*/true>
        <<<nblk_d, 256, 0, stream>>>(mean, xb, W1cat, b1, h, N);

    // ---- Layer 2: h -> out (f32) ----
    k_gather<D1><<<2048, 256, 0, stream>>>(h, cnt, bin, mean);
    k_mdense<D1, /*RELU=*/false, /*OUT_BF16=*/false>
        <<<nblk_d, 256, 0, stream>>>(mean, h, W2cat, b2, out, N);
}